// Round 10
// baseline (296.575 us; speedup 1.0000x reference)
//
#include <hip/hip_runtime.h>
#include <hip/hip_bf16.h>
#include <stdint.h>

// GAT v6: 3-kernel pipeline with per-node static edge slots (no binning layer).
//   k_gemm_s: f32 tile GEMM -> bf16 z + LDS-transpose score epilogue
//   k_bin3:   per-edge global-atomic slot claim + ushort src scatter
//   k_gatw:   per-node (1 wave) register-accumulating gather (gat4 structure)
// N=50000, E=1.6M, IN=128, OUT=32, H=4 (H*O=128).
// deg ~ Poisson(32); SLOT=96 => overflow prob ~1e-15 (and defensively clamped).

#define NN 50000
#define NE 1600000
#define IN_DIM 128
#define OC 128
#define SLOT 96
#define CNTP 16   // cnt padding stride in ints (64 B -> one L2 line per node)

__device__ __forceinline__ float lrelu(float x) { return x >= 0.f ? x : 0.01f * x; }

// ------------------------------------------- projection + fused score tables
// z = h @ Wc^T (f32 accum, bf16 out). Epilogue: stage acc in LDS ([n][h][33]
// bank-free layout), one (node,head) dot per thread. smem reused (aliased).
__global__ __launch_bounds__(256) void k_gemm_s(const float* __restrict__ h,
                                                const float* __restrict__ W,
                                                const float* __restrict__ a,
                                                __hip_bfloat16* __restrict__ zb,
                                                float* __restrict__ ssrc,
                                                float* __restrict__ sdst) {
    __shared__ float smem[64 * 65 + 64 * 129];   // 49,664 B
    float (*hs)[65]  = reinterpret_cast<float(*)[65]>(smem);
    float (*ws)[129] = reinterpret_cast<float(*)[129]>(smem + 64 * 65);
    float* zs = smem;                            // epilogue alias: 64*132 floats

    const int t  = threadIdx.x;
    const int n0 = blockIdx.x * 64;
    const int tx = t & 31;   // channel c = tx + 32*j (head j)
    const int ty = t >> 5;   // node n = ty + 8*i

    float acc[8][4];
#pragma unroll
    for (int i = 0; i < 8; ++i)
#pragma unroll
        for (int j = 0; j < 4; ++j) acc[i][j] = 0.f;

    for (int kt = 0; kt < IN_DIM; kt += 64) {
#pragma unroll
        for (int s = 0; s < 4; ++s) {
            const int idx4 = t + s * 256;
            const int n    = idx4 >> 4;
            const int kk   = (idx4 & 15) << 2;
            const int gn   = n0 + n;
            float4 v = make_float4(0.f, 0.f, 0.f, 0.f);
            if (gn < NN) v = *(const float4*)(h + (size_t)gn * IN_DIM + kt + kk);
            hs[kk + 0][n] = v.x; hs[kk + 1][n] = v.y;
            hs[kk + 2][n] = v.z; hs[kk + 3][n] = v.w;
        }
#pragma unroll
        for (int s = 0; s < 8; ++s) {
            const int idx4 = t + s * 256;
            const int c    = idx4 >> 4;
            const int kk   = (idx4 & 15) << 2;
            const float4 v = *(const float4*)(W + (size_t)c * IN_DIM + kt + kk);
            ws[kk + 0][c] = v.x; ws[kk + 1][c] = v.y;
            ws[kk + 2][c] = v.z; ws[kk + 3][c] = v.w;
        }
        __syncthreads();
#pragma unroll 4
        for (int k = 0; k < 64; ++k) {
            float wv[4], hv[8];
#pragma unroll
            for (int j = 0; j < 4; ++j) wv[j] = ws[k][tx + 32 * j];
#pragma unroll
            for (int i = 0; i < 8; ++i) hv[i] = hs[k][ty + 8 * i];
#pragma unroll
            for (int i = 0; i < 8; ++i)
#pragma unroll
                for (int j = 0; j < 4; ++j) acc[i][j] = fmaf(hv[i], wv[j], acc[i][j]);
        }
        __syncthreads();
    }
    // z out (bf16), and stage acc into zs (k-loop done; smem reuse is safe)
#pragma unroll
    for (int i = 0; i < 8; ++i) {
        const int gn = n0 + ty + 8 * i;
        if (gn < NN) {
#pragma unroll
            for (int j = 0; j < 4; ++j)
                zb[(size_t)gn * OC + tx + 32 * j] = __float2bfloat16(acc[i][j]);
        }
#pragma unroll
        for (int j = 0; j < 4; ++j)
            zs[(ty + 8 * i) * 132 + j * 33 + tx] = acc[i][j];
    }
    __syncthreads();
    // one (node, head) pair per thread: 32-wide dot from LDS
    {
        const int n  = t >> 2;
        const int hh = t & 3;
        const float* zrow = zs + n * 132 + hh * 33;
        const float* av   = a + hh * 64;
        float ps = 0.f, pd = 0.f;
#pragma unroll
        for (int i = 0; i < 32; ++i) {
            const float zv = zrow[i];
            ps = fmaf(zv, av[i],      ps);
            pd = fmaf(zv, av[32 + i], pd);
        }
        const int gn = n0 + n;
        if (gn < NN) {
            ssrc[gn * 4 + hh] = ps;
            sdst[gn * 4 + hh] = pd;
        }
    }
}

// ------------------------- per-edge slot claim (global atomics, padded lines)
__global__ __launch_bounds__(256) void k_bin3(const int* __restrict__ src,
                                              const int* __restrict__ dst,
                                              int* __restrict__ cnt,
                                              unsigned short* __restrict__ esrc) {
    const int e = blockIdx.x * 256 + threadIdx.x;
    if (e < NE) {
        const int d   = dst[e];
        const int old = atomicAdd(&cnt[d * CNTP], 1);
        if (old < SLOT) esrc[d * SLOT + old] = (unsigned short)src[e];
    }
}

// --------------------------------------------------------------- main per-node
// 1 wave per dst node (4 nodes/block). 16-lane group g handles edge 4*it+g;
// lane16 covers channels [8*lane16, 8*lane16+8) via one dwordx4 from zb.
// {sid, w} pairs staged in LDS.
__global__ __launch_bounds__(256) void k_gatw(const uint32_t* __restrict__ zb,
                                              const float4* __restrict__ ssrc,
                                              const float4* __restrict__ sdst,
                                              const int* __restrict__ cnt,
                                              const unsigned short* __restrict__ esrc,
                                              float* __restrict__ out) {
    __shared__ float2 lp[4][64][4];   // [ty][edge][head] = {sid_bits, w}  (8 KB)
    const int ty     = threadIdx.y;
    const int node   = blockIdx.x * 4 + ty;
    const int lane   = threadIdx.x;
    const int lane16 = lane & 15;
    const int grp    = lane >> 4;
    const int hsel   = lane16 >> 2;
    const int s0     = node * SLOT;
    const int d      = min(cnt[node * CNTP], SLOT);
    const float4 sd  = sdst[node];

    float acc[8];
#pragma unroll
    for (int i = 0; i < 8; ++i) acc[i] = 0.f;
    float dn0 = 0.f, dn1 = 0.f, dn2 = 0.f, dn3 = 0.f;

    for (int base = 0; base < d; base += 64) {
        const int myj = base + lane;
        int sid_l = 0;
        float x0 = 0.f, x1 = 0.f, x2 = 0.f, x3 = 0.f;
        if (myj < d) {
            sid_l = esrc[s0 + myj];
            const float4 ss = ssrc[sid_l];
            x0 = __expf(lrelu(ss.x + sd.x));
            x1 = __expf(lrelu(ss.y + sd.y));
            x2 = __expf(lrelu(ss.z + sd.z));
            x3 = __expf(lrelu(ss.w + sd.w));
            dn0 += x0; dn1 += x1; dn2 += x2; dn3 += x3;
        }
        const float sf = __builtin_bit_cast(float, sid_l);
        float4* lq = (float4*)&lp[ty][lane][0];
        lq[0] = make_float4(sf, x0, sf, x1);
        lq[1] = make_float4(sf, x2, sf, x3);

        const int cntc = min(64, d - base);
        const int nit  = (cntc + 3) >> 2;
#pragma unroll 2
        for (int it = 0; it < nit; ++it) {
            const int e4 = (it << 2) + grp;
            const float2 pw = lp[ty][e4][hsel];
            const int   sid = __builtin_bit_cast(int, pw.x);
            const float w   = pw.y;
            const uint4 Z = *(const uint4*)(zb + ((size_t)sid << 6) + (lane16 << 2));
            acc[0] = fmaf(w, __builtin_bit_cast(float, Z.x << 16),          acc[0]);
            acc[1] = fmaf(w, __builtin_bit_cast(float, Z.x & 0xffff0000u),  acc[1]);
            acc[2] = fmaf(w, __builtin_bit_cast(float, Z.y << 16),          acc[2]);
            acc[3] = fmaf(w, __builtin_bit_cast(float, Z.y & 0xffff0000u),  acc[3]);
            acc[4] = fmaf(w, __builtin_bit_cast(float, Z.z << 16),          acc[4]);
            acc[5] = fmaf(w, __builtin_bit_cast(float, Z.z & 0xffff0000u),  acc[5]);
            acc[6] = fmaf(w, __builtin_bit_cast(float, Z.w << 16),          acc[6]);
            acc[7] = fmaf(w, __builtin_bit_cast(float, Z.w & 0xffff0000u),  acc[7]);
        }
    }
    // combine the 4 groups (same channels in lanes l, l^16, l^32, l^48)
#pragma unroll
    for (int i = 0; i < 8; ++i) {
        acc[i] += __shfl_xor(acc[i], 16);
        acc[i] += __shfl_xor(acc[i], 32);
    }
    // denominators (per head, summed over all lanes)
#pragma unroll
    for (int off = 32; off > 0; off >>= 1) {
        dn0 += __shfl_xor(dn0, off);
        dn1 += __shfl_xor(dn1, off);
        dn2 += __shfl_xor(dn2, off);
        dn3 += __shfl_xor(dn3, off);
    }
    const float dsel = (hsel == 0) ? dn0 : (hsel == 1) ? dn1 : (hsel == 2) ? dn2 : dn3;
    const float inv  = (dsel > 0.f) ? 1.0f / dsel : 0.f;
    if (grp == 0) {
        float* op = out + (size_t)node * OC + (lane16 << 3);
        *(float4*)(op)     = make_float4(acc[0]*inv, acc[1]*inv, acc[2]*inv, acc[3]*inv);
        *(float4*)(op + 4) = make_float4(acc[4]*inv, acc[5]*inv, acc[6]*inv, acc[7]*inv);
    }
}

// ------------------------------------------------------------------- launcher
extern "C" void kernel_launch(void* const* d_in, const int* in_sizes, int n_in,
                              void* d_out, int out_size, void* d_ws, size_t ws_size,
                              hipStream_t stream) {
    const float* h_in = (const float*)d_in[0];
    const float* W    = (const float*)d_in[1];
    const float* a    = (const float*)d_in[2];
    const int*   src  = (const int*)d_in[3];
    const int*   dst  = (const int*)d_in[4];
    float*       out  = (float*)d_out;

    char* w = (char*)d_ws;
    __hip_bfloat16* zb   = (__hip_bfloat16*)(w);          // 12,800,000 B
    float*    ssrc       = (float*)(w + 12800000);        //    800,000 B
    float*    sdst       = (float*)(w + 13600000);        //    800,000 B
    int*      cnt        = (int*)(w + 14400000);          //  3,200,000 B (50k*64B)
    unsigned short* esrc = (unsigned short*)(w + 17600000); // 9,600,000 B (50k*96*2)
    // total 27,200,000 B

    hipMemsetAsync(cnt, 0, 3200000, stream);

    k_gemm_s<<<(NN + 63) / 64, 256, 0, stream>>>(h_in, W, a, zb, ssrc, sdst);
    k_bin3  <<<(NE + 255) / 256, 256, 0, stream>>>(src, dst, cnt, esrc);
    k_gatw  <<<NN / 4, dim3(64, 4), 0, stream>>>((const uint32_t*)zb,
                                                 (const float4*)ssrc, (const float4*)sdst,
                                                 cnt, esrc, out);
}

// Round 11
// 225.502 us; speedup vs baseline: 1.3152x; 1.3152x over previous
//
#include <hip/hip_runtime.h>
#include <hip/hip_bf16.h>
#include <stdint.h>

// GAT v7: 3 kernels + memset.
//   k_gemm_s: 128x128 tile GEMM (8x8/thread, ds_read_b128 both operands,
//             K-tile 32) -> bf16 z + shfl score epilogue
//   k_bin2:   bin edges by 64-node dst bucket (relative cursors, memset-init)
//   k_gatb:   per-bucket LDS sort to per-node lists + per-wave register gather
// N=50000, E=1.6M, IN=128, OUT=32, H=4 (H*O=128)
// Round-10 lessons: random fine scatter = 1 dirty line/edge (bin3 FAILED);
// GEMM was LDS-instruction-bound (12 b32 reads / 32 FMA) -> b128 restructure.

#define NN 50000
#define NE 1600000
#define IN_DIM 128
#define OC 128
#define NBSH 6
#define NBUCK ((NN + 63) >> 6)   // 782 buckets of 64 dst nodes
#define CAP 2560                 // bucket capacity: mean 2046 + ~11 sigma
#define CURS 16                  // cursor stride (ints) = 64 B padding
#define BIN_BLOCKS 256
#define EPB ((NE + BIN_BLOCKS - 1) / BIN_BLOCKS)   // 6250 edges per bin block

__device__ __forceinline__ float lrelu(float x) { return x >= 0.f ? x : 0.01f * x; }

// ------------------------------------------- projection + fused score tables
// 128 nodes x 128 ch per block; thread (u=t&15, v=t>>4) owns nodes 8u..8u+7,
// channels 8v..8v+7 (head v>>2). Per k: 2+2 ds_read_b128 feed 64 FMAs.
__global__ __launch_bounds__(256) void k_gemm_s(const float* __restrict__ h,
                                                const float* __restrict__ W,
                                                const float* __restrict__ a,
                                                __hip_bfloat16* __restrict__ zb,
                                                float* __restrict__ ssrc,
                                                float* __restrict__ sdst) {
    __shared__ float hs[32][132];   // [k][node]    16,896 B
    __shared__ float ws[32][132];   // [k][channel] 16,896 B
    const int t  = threadIdx.x;
    const int n0 = blockIdx.x * 128;
    const int u  = t & 15;    // node group: nodes 8u..8u+7
    const int v  = t >> 4;    // ch group:   ch 8v..8v+7, head v>>2

    float acc[8][8];
#pragma unroll
    for (int i = 0; i < 8; ++i)
#pragma unroll
        for (int j = 0; j < 8; ++j) acc[i][j] = 0.f;

    for (int kt = 0; kt < IN_DIM; kt += 32) {
#pragma unroll
        for (int s = 0; s < 4; ++s) {
            const int idx = t + s * 256;        // 0..1023
            const int r   = idx >> 3;           // 0..127
            const int kk  = (idx & 7) << 2;     // 0..28
            const int gn  = n0 + r;
            float4 hv = make_float4(0.f, 0.f, 0.f, 0.f);
            if (gn < NN) hv = *(const float4*)(h + (size_t)gn * IN_DIM + kt + kk);
            hs[kk + 0][r] = hv.x; hs[kk + 1][r] = hv.y;
            hs[kk + 2][r] = hv.z; hs[kk + 3][r] = hv.w;
            const float4 wv = *(const float4*)(W + (size_t)r * IN_DIM + kt + kk);
            ws[kk + 0][r] = wv.x; ws[kk + 1][r] = wv.y;
            ws[kk + 2][r] = wv.z; ws[kk + 3][r] = wv.w;
        }
        __syncthreads();
#pragma unroll 4
        for (int k = 0; k < 32; ++k) {
            const float4 h0 = *(const float4*)&hs[k][8 * u];
            const float4 h1 = *(const float4*)&hs[k][8 * u + 4];
            const float4 w0 = *(const float4*)&ws[k][8 * v];
            const float4 w1 = *(const float4*)&ws[k][8 * v + 4];
            const float hv[8] = {h0.x, h0.y, h0.z, h0.w, h1.x, h1.y, h1.z, h1.w};
            const float wv[8] = {w0.x, w0.y, w0.z, w0.w, w1.x, w1.y, w1.z, w1.w};
#pragma unroll
            for (int i = 0; i < 8; ++i)
#pragma unroll
                for (int j = 0; j < 8; ++j) acc[i][j] = fmaf(hv[i], wv[j], acc[i][j]);
        }
        __syncthreads();
    }

    // z out (bf16x8 = one dwordx4 store per node-row chunk)
#pragma unroll
    for (int i = 0; i < 8; ++i) {
        const int gn = n0 + 8 * u + i;
        if (gn < NN) {
            __hip_bfloat16 bv[8];
#pragma unroll
            for (int j = 0; j < 8; ++j) bv[j] = __float2bfloat16(acc[i][j]);
            *(uint4*)(zb + (size_t)gn * OC + 8 * v) = *(const uint4*)bv;
        }
    }

    // fused scores: head = v>>2; within-head ch offset = 8*(v&3)+j.
    const int head = v >> 2;
    float as[8], ad[8];
#pragma unroll
    for (int j = 0; j < 8; ++j) {
        as[j] = a[head * 64 + 8 * (v & 3) + j];
        ad[j] = a[head * 64 + 32 + 8 * (v & 3) + j];
    }
#pragma unroll
    for (int i = 0; i < 8; ++i) {
        float ps = 0.f, pd = 0.f;
#pragma unroll
        for (int j = 0; j < 8; ++j) {
            ps = fmaf(acc[i][j], as[j], ps);
            pd = fmaf(acc[i][j], ad[j], pd);
        }
        // reduce over the 4 lanes with same u, head (lane = (v&3)*16 + u)
        ps += __shfl_xor(ps, 16); ps += __shfl_xor(ps, 32);
        pd += __shfl_xor(pd, 16); pd += __shfl_xor(pd, 32);
        const int gn = n0 + 8 * u + i;
        if ((v & 3) == 0 && gn < NN) {
            ssrc[gn * 4 + head] = ps;
            sdst[gn * 4 + head] = pd;
        }
    }
}

// ------------------- bin edges: LDS count -> per-(block,bucket) reserve -> scatter
// cursors are RELATIVE (start at 0 via memset).
__global__ __launch_bounds__(256) void k_bin2(const int* __restrict__ src,
                                              const int* __restrict__ dst,
                                              int* __restrict__ cursor,
                                              uint32_t* __restrict__ ebuf) {
    __shared__ int hb[NBUCK];
    __shared__ int ofs[NBUCK];
    const int t    = threadIdx.x;
    const int ebeg = blockIdx.x * EPB;
    const int eend = min(ebeg + EPB, NE);
    for (int i = t; i < NBUCK; i += 256) hb[i] = 0;
    __syncthreads();
    for (int e = ebeg + t; e < eend; e += 256)
        atomicAdd(&hb[dst[e] >> NBSH], 1);
    __syncthreads();
    for (int i = t; i < NBUCK; i += 256) {
        const int c = hb[i];
        ofs[i] = (c > 0) ? atomicAdd(&cursor[i * CURS], c) : 0;
        hb[i] = 0;
    }
    __syncthreads();
    for (int e = ebeg + t; e < eend; e += 256) {
        const int d = dst[e];
        const int b = d >> NBSH;
        const int p = ofs[b] + atomicAdd(&hb[b], 1);
        if (p < CAP)   // defensive (statistically impossible overflow)
            ebuf[b * CAP + p] = (uint32_t)src[e] | ((uint32_t)(d & 63) << 16);
    }
}

// ---------------- per-bucket: LDS sort to per-node lists + register aggregate
__global__ __launch_bounds__(512) void k_gatb(const uint32_t* __restrict__ zb,
                                              const float4* __restrict__ ssrc,
                                              const float4* __restrict__ sdst,
                                              const int* __restrict__ cursor,
                                              const uint32_t* __restrict__ ebuf,
                                              float* __restrict__ out) {
    __shared__ unsigned short elist[CAP];   //  5120 B
    __shared__ float2 lp[8][64][4];         // 16384 B  [wave][edge][head]={sid,w}
    __shared__ float4 sdl[64];              //  1024 B
    __shared__ int cnt[64], cur[64], basel[64];
    const int b     = blockIdx.x;
    const int tid   = threadIdx.x;
    const int bbase = b * CAP;
    const int ecnt  = min(cursor[b * CURS], CAP);

    if (tid < 64) cnt[tid] = 0;
    if (tid >= 64 && tid < 128) {
        const int gnode = (b << NBSH) + tid - 64;
        sdl[tid - 64] = (gnode < NN) ? sdst[gnode] : make_float4(0.f, 0.f, 0.f, 0.f);
    }
    __syncthreads();
    for (int i = tid; i < ecnt; i += 512)
        atomicAdd(&cnt[(ebuf[bbase + i] >> 16) & 63], 1);
    __syncthreads();
    if (tid < 64) {
        const int d = cnt[tid];
        int v = d;
#pragma unroll
        for (int off = 1; off < 64; off <<= 1) {
            const int uu = __shfl_up(v, off);
            if (tid >= off) v += uu;
        }
        basel[tid] = v - d;
        cur[tid]   = v - d;
    }
    __syncthreads();
    for (int i = tid; i < ecnt; i += 512) {
        const uint32_t v = ebuf[bbase + i];
        const int dl = (v >> 16) & 63;
        const int p  = atomicAdd(&cur[dl], 1);
        elist[p] = (unsigned short)(v & 0xffffu);
    }
    __syncthreads();

    // phase 2: one wave per node, 8 nodes per wave
    const int wid    = tid >> 6;
    const int lane   = tid & 63;
    const int lane16 = lane & 15;
    const int grp    = lane >> 4;
    const int hsel   = lane16 >> 2;
#pragma unroll 1
    for (int nl = wid * 8; nl < wid * 8 + 8; ++nl) {
        const int gnode = (b << NBSH) + nl;
        if (gnode >= NN) break;                 // wave-uniform
        const int d  = cnt[nl];
        const int s0 = basel[nl];
        const float4 sd = sdl[nl];

        float acc[8];
#pragma unroll
        for (int i = 0; i < 8; ++i) acc[i] = 0.f;
        float dn0 = 0.f, dn1 = 0.f, dn2 = 0.f, dn3 = 0.f;

        for (int base = 0; base < d; base += 64) {
            const int myj = base + lane;
            int sid_l = 0;
            float x0 = 0.f, x1 = 0.f, x2 = 0.f, x3 = 0.f;
            if (myj < d) {
                sid_l = elist[s0 + myj];
                const float4 ss = ssrc[sid_l];
                x0 = __expf(lrelu(ss.x + sd.x));
                x1 = __expf(lrelu(ss.y + sd.y));
                x2 = __expf(lrelu(ss.z + sd.z));
                x3 = __expf(lrelu(ss.w + sd.w));
                dn0 += x0; dn1 += x1; dn2 += x2; dn3 += x3;
            }
            const float sf = __builtin_bit_cast(float, sid_l);
            float4* lq = (float4*)&lp[wid][lane][0];
            lq[0] = make_float4(sf, x0, sf, x1);
            lq[1] = make_float4(sf, x2, sf, x3);

            const int cntc = min(64, d - base);
            const int nit  = (cntc + 3) >> 2;
#pragma unroll 2
            for (int it = 0; it < nit; ++it) {
                const int e4 = (it << 2) + grp;
                const float2 pw = lp[wid][e4][hsel];
                const int   sid = __builtin_bit_cast(int, pw.x);
                const float w   = pw.y;
                const uint4 Z = *(const uint4*)(zb + ((size_t)sid << 6) + (lane16 << 2));
                acc[0] = fmaf(w, __builtin_bit_cast(float, Z.x << 16),          acc[0]);
                acc[1] = fmaf(w, __builtin_bit_cast(float, Z.x & 0xffff0000u),  acc[1]);
                acc[2] = fmaf(w, __builtin_bit_cast(float, Z.y << 16),          acc[2]);
                acc[3] = fmaf(w, __builtin_bit_cast(float, Z.y & 0xffff0000u),  acc[3]);
                acc[4] = fmaf(w, __builtin_bit_cast(float, Z.z << 16),          acc[4]);
                acc[5] = fmaf(w, __builtin_bit_cast(float, Z.z & 0xffff0000u),  acc[5]);
                acc[6] = fmaf(w, __builtin_bit_cast(float, Z.w << 16),          acc[6]);
                acc[7] = fmaf(w, __builtin_bit_cast(float, Z.w & 0xffff0000u),  acc[7]);
            }
        }
#pragma unroll
        for (int i = 0; i < 8; ++i) {
            acc[i] += __shfl_xor(acc[i], 16);
            acc[i] += __shfl_xor(acc[i], 32);
        }
#pragma unroll
        for (int off = 32; off > 0; off >>= 1) {
            dn0 += __shfl_xor(dn0, off);
            dn1 += __shfl_xor(dn1, off);
            dn2 += __shfl_xor(dn2, off);
            dn3 += __shfl_xor(dn3, off);
        }
        const float dsel = (hsel == 0) ? dn0 : (hsel == 1) ? dn1 : (hsel == 2) ? dn2 : dn3;
        const float inv  = (dsel > 0.f) ? 1.0f / dsel : 0.f;
        if (grp == 0) {
            float* op = out + (size_t)gnode * OC + (lane16 << 3);
            *(float4*)(op)     = make_float4(acc[0]*inv, acc[1]*inv, acc[2]*inv, acc[3]*inv);
            *(float4*)(op + 4) = make_float4(acc[4]*inv, acc[5]*inv, acc[6]*inv, acc[7]*inv);
        }
    }
}

// ------------------------------------------------------------------- launcher
extern "C" void kernel_launch(void* const* d_in, const int* in_sizes, int n_in,
                              void* d_out, int out_size, void* d_ws, size_t ws_size,
                              hipStream_t stream) {
    const float* h_in = (const float*)d_in[0];
    const float* W    = (const float*)d_in[1];
    const float* a    = (const float*)d_in[2];
    const int*   src  = (const int*)d_in[3];
    const int*   dst  = (const int*)d_in[4];
    float*       out  = (float*)d_out;

    char* w = (char*)d_ws;
    __hip_bfloat16* zb = (__hip_bfloat16*)(w);          // 12,800,000 B
    float*    ssrc     = (float*)(w + 12800000);        //    800,000 B
    float*    sdst     = (float*)(w + 13600000);        //    800,000 B
    int*      cursor   = (int*)(w + 14400000);          //     50,048 B
    uint32_t* ebuf     = (uint32_t*)(w + 14450048);     //  8,007,680 B (782*2560*4)
    // total 22,457,728 B

    hipMemsetAsync(cursor, 0, NBUCK * CURS * 4, stream);

    k_gemm_s<<<(NN + 127) / 128, 256, 0, stream>>>(h_in, W, a, zb, ssrc, sdst);
    k_bin2  <<<BIN_BLOCKS, 256, 0, stream>>>(src, dst, cursor, ebuf);
    k_gatb  <<<NBUCK, 512, 0, stream>>>((const uint32_t*)zb,
                                        (const float4*)ssrc, (const float4*)sdst,
                                        cursor, ebuf, out);
}

// Round 12
// 201.829 us; speedup vs baseline: 1.4694x; 1.1173x over previous
//
#include <hip/hip_runtime.h>
#include <hip/hip_bf16.h>
#include <stdint.h>

// GAT v8: 2 kernels + memset.
//   k_front: blocks [0,391) = 128x128-tile GEMM (-> bf16 z + score epilogue);
//            blocks [391,647) = edge binning by 64-node dst bucket.
//            Independent inputs -> concurrent execution, one dispatch.
//   k_gatb:  per-bucket LDS sort to per-node lists + per-wave register gather
// N=50000, E=1.6M, IN=128, OUT=32, H=4 (H*O=128)

#define NN 50000
#define NE 1600000
#define IN_DIM 128
#define OC 128
#define NBSH 6
#define NBUCK ((NN + 63) >> 6)   // 782 buckets of 64 dst nodes
#define CAP 2560                 // bucket capacity: mean 2046 + ~11 sigma
#define CURS 16                  // cursor stride (ints) = 64 B padding
#define GEMM_BLOCKS ((NN + 127) / 128)             // 391
#define BIN_BLOCKS 256
#define EPB ((NE + BIN_BLOCKS - 1) / BIN_BLOCKS)   // 6250 edges per bin block

__device__ __forceinline__ float lrelu(float x) { return x >= 0.f ? x : 0.01f * x; }

// --------------------------------------------------- fused front: GEMM || bin
__global__ __launch_bounds__(256) void k_front(const float* __restrict__ h,
                                               const float* __restrict__ W,
                                               const float* __restrict__ a,
                                               const int* __restrict__ src,
                                               const int* __restrict__ dst,
                                               __hip_bfloat16* __restrict__ zb,
                                               float* __restrict__ ssrc,
                                               float* __restrict__ sdst,
                                               int* __restrict__ cursor,
                                               uint32_t* __restrict__ ebuf) {
    __shared__ float smem[2 * 32 * 132];   // 33,792 B (gemm) / reused by bin
    const int t = threadIdx.x;

    if (blockIdx.x < GEMM_BLOCKS) {
        // ---------------- GEMM part: 128 nodes x 128 ch; 8x8 per thread ----
        float (*hs)[132] = reinterpret_cast<float(*)[132]>(smem);
        float (*ws)[132] = reinterpret_cast<float(*)[132]>(smem + 32 * 132);
        const int n0 = blockIdx.x * 128;
        const int u  = t & 15;    // nodes 8u..8u+7
        const int v  = t >> 4;    // channels 8v..8v+7, head v>>2

        float acc[8][8];
#pragma unroll
        for (int i = 0; i < 8; ++i)
#pragma unroll
            for (int j = 0; j < 8; ++j) acc[i][j] = 0.f;

        for (int kt = 0; kt < IN_DIM; kt += 32) {
#pragma unroll
            for (int s = 0; s < 4; ++s) {
                const int idx = t + s * 256;
                const int r   = idx >> 3;
                const int kk  = (idx & 7) << 2;
                const int gn  = n0 + r;
                float4 hv = make_float4(0.f, 0.f, 0.f, 0.f);
                if (gn < NN) hv = *(const float4*)(h + (size_t)gn * IN_DIM + kt + kk);
                hs[kk + 0][r] = hv.x; hs[kk + 1][r] = hv.y;
                hs[kk + 2][r] = hv.z; hs[kk + 3][r] = hv.w;
                const float4 wv = *(const float4*)(W + (size_t)r * IN_DIM + kt + kk);
                ws[kk + 0][r] = wv.x; ws[kk + 1][r] = wv.y;
                ws[kk + 2][r] = wv.z; ws[kk + 3][r] = wv.w;
            }
            __syncthreads();
#pragma unroll 4
            for (int k = 0; k < 32; ++k) {
                const float4 h0 = *(const float4*)&hs[k][8 * u];
                const float4 h1 = *(const float4*)&hs[k][8 * u + 4];
                const float4 w0 = *(const float4*)&ws[k][8 * v];
                const float4 w1 = *(const float4*)&ws[k][8 * v + 4];
                const float hv[8] = {h0.x, h0.y, h0.z, h0.w, h1.x, h1.y, h1.z, h1.w};
                const float wv[8] = {w0.x, w0.y, w0.z, w0.w, w1.x, w1.y, w1.z, w1.w};
#pragma unroll
                for (int i = 0; i < 8; ++i)
#pragma unroll
                    for (int j = 0; j < 8; ++j) acc[i][j] = fmaf(hv[i], wv[j], acc[i][j]);
            }
            __syncthreads();
        }

#pragma unroll
        for (int i = 0; i < 8; ++i) {
            const int gn = n0 + 8 * u + i;
            if (gn < NN) {
                __hip_bfloat16 bv[8];
#pragma unroll
                for (int j = 0; j < 8; ++j) bv[j] = __float2bfloat16(acc[i][j]);
                *(uint4*)(zb + (size_t)gn * OC + 8 * v) = *(const uint4*)bv;
            }
        }

        const int head = v >> 2;
        float as[8], ad[8];
#pragma unroll
        for (int j = 0; j < 8; ++j) {
            as[j] = a[head * 64 + 8 * (v & 3) + j];
            ad[j] = a[head * 64 + 32 + 8 * (v & 3) + j];
        }
#pragma unroll
        for (int i = 0; i < 8; ++i) {
            float ps = 0.f, pd = 0.f;
#pragma unroll
            for (int j = 0; j < 8; ++j) {
                ps = fmaf(acc[i][j], as[j], ps);
                pd = fmaf(acc[i][j], ad[j], pd);
            }
            ps += __shfl_xor(ps, 16); ps += __shfl_xor(ps, 32);
            pd += __shfl_xor(pd, 16); pd += __shfl_xor(pd, 32);
            const int gn = n0 + 8 * u + i;
            if ((v & 3) == 0 && gn < NN) {
                ssrc[gn * 4 + head] = ps;
                sdst[gn * 4 + head] = pd;
            }
        }
    } else {
        // ---------------- bin part: count -> reserve -> scatter ------------
        int* hb  = (int*)smem;
        int* ofs = hb + NBUCK;
        const int bb   = blockIdx.x - GEMM_BLOCKS;
        const int ebeg = bb * EPB;
        const int eend = min(ebeg + EPB, NE);
        for (int i = t; i < NBUCK; i += 256) hb[i] = 0;
        __syncthreads();
        for (int e = ebeg + t; e < eend; e += 256)
            atomicAdd(&hb[dst[e] >> NBSH], 1);
        __syncthreads();
        for (int i = t; i < NBUCK; i += 256) {
            const int c = hb[i];
            ofs[i] = (c > 0) ? atomicAdd(&cursor[i * CURS], c) : 0;
            hb[i] = 0;
        }
        __syncthreads();
        for (int e = ebeg + t; e < eend; e += 256) {
            const int d = dst[e];
            const int b = d >> NBSH;
            const int p = ofs[b] + atomicAdd(&hb[b], 1);
            if (p < CAP)   // defensive (statistically impossible overflow)
                ebuf[b * CAP + p] = (uint32_t)src[e] | ((uint32_t)(d & 63) << 16);
        }
    }
}

// ---------------- per-bucket: LDS sort to per-node lists + register aggregate
__global__ __launch_bounds__(512) void k_gatb(const uint32_t* __restrict__ zb,
                                              const float4* __restrict__ ssrc,
                                              const float4* __restrict__ sdst,
                                              const int* __restrict__ cursor,
                                              const uint32_t* __restrict__ ebuf,
                                              float* __restrict__ out) {
    __shared__ unsigned short elist[CAP];   //  5120 B
    __shared__ float2 lp[8][64][4];         // 16384 B  [wave][edge][head]={sid,w}
    __shared__ float4 sdl[64];              //  1024 B
    __shared__ int cnt[64], cur[64], basel[64];
    const int b     = blockIdx.x;
    const int tid   = threadIdx.x;
    const int bbase = b * CAP;
    const int ecnt  = min(cursor[b * CURS], CAP);

    if (tid < 64) cnt[tid] = 0;
    if (tid >= 64 && tid < 128) {
        const int gnode = (b << NBSH) + tid - 64;
        sdl[tid - 64] = (gnode < NN) ? sdst[gnode] : make_float4(0.f, 0.f, 0.f, 0.f);
    }
    __syncthreads();
    for (int i = tid; i < ecnt; i += 512)
        atomicAdd(&cnt[(ebuf[bbase + i] >> 16) & 63], 1);
    __syncthreads();
    if (tid < 64) {
        const int d = cnt[tid];
        int v = d;
#pragma unroll
        for (int off = 1; off < 64; off <<= 1) {
            const int uu = __shfl_up(v, off);
            if (tid >= off) v += uu;
        }
        basel[tid] = v - d;
        cur[tid]   = v - d;
    }
    __syncthreads();
    for (int i = tid; i < ecnt; i += 512) {
        const uint32_t v = ebuf[bbase + i];
        const int dl = (v >> 16) & 63;
        const int p  = atomicAdd(&cur[dl], 1);
        elist[p] = (unsigned short)(v & 0xffffu);
    }
    __syncthreads();

    // phase 2: one wave per node, 8 nodes per wave
    const int wid    = tid >> 6;
    const int lane   = tid & 63;
    const int lane16 = lane & 15;
    const int grp    = lane >> 4;
    const int hsel   = lane16 >> 2;
#pragma unroll 1
    for (int nl = wid * 8; nl < wid * 8 + 8; ++nl) {
        const int gnode = (b << NBSH) + nl;
        if (gnode >= NN) break;                 // wave-uniform
        const int d  = cnt[nl];
        const int s0 = basel[nl];
        const float4 sd = sdl[nl];

        float acc[8];
#pragma unroll
        for (int i = 0; i < 8; ++i) acc[i] = 0.f;
        float dn0 = 0.f, dn1 = 0.f, dn2 = 0.f, dn3 = 0.f;

        for (int base = 0; base < d; base += 64) {
            const int myj = base + lane;
            int sid_l = 0;
            float x0 = 0.f, x1 = 0.f, x2 = 0.f, x3 = 0.f;
            if (myj < d) {
                sid_l = elist[s0 + myj];
                const float4 ss = ssrc[sid_l];
                x0 = __expf(lrelu(ss.x + sd.x));
                x1 = __expf(lrelu(ss.y + sd.y));
                x2 = __expf(lrelu(ss.z + sd.z));
                x3 = __expf(lrelu(ss.w + sd.w));
                dn0 += x0; dn1 += x1; dn2 += x2; dn3 += x3;
            }
            const float sf = __builtin_bit_cast(float, sid_l);
            float4* lq = (float4*)&lp[wid][lane][0];
            lq[0] = make_float4(sf, x0, sf, x1);
            lq[1] = make_float4(sf, x2, sf, x3);

            const int cntc = min(64, d - base);
            const int nit  = (cntc + 3) >> 2;
#pragma unroll 2
            for (int it = 0; it < nit; ++it) {
                const int e4 = (it << 2) + grp;
                const float2 pw = lp[wid][e4][hsel];
                const int   sid = __builtin_bit_cast(int, pw.x);
                const float w   = pw.y;
                const uint4 Z = *(const uint4*)(zb + ((size_t)sid << 6) + (lane16 << 2));
                acc[0] = fmaf(w, __builtin_bit_cast(float, Z.x << 16),          acc[0]);
                acc[1] = fmaf(w, __builtin_bit_cast(float, Z.x & 0xffff0000u),  acc[1]);
                acc[2] = fmaf(w, __builtin_bit_cast(float, Z.y << 16),          acc[2]);
                acc[3] = fmaf(w, __builtin_bit_cast(float, Z.y & 0xffff0000u),  acc[3]);
                acc[4] = fmaf(w, __builtin_bit_cast(float, Z.z << 16),          acc[4]);
                acc[5] = fmaf(w, __builtin_bit_cast(float, Z.z & 0xffff0000u),  acc[5]);
                acc[6] = fmaf(w, __builtin_bit_cast(float, Z.w << 16),          acc[6]);
                acc[7] = fmaf(w, __builtin_bit_cast(float, Z.w & 0xffff0000u),  acc[7]);
            }
        }
#pragma unroll
        for (int i = 0; i < 8; ++i) {
            acc[i] += __shfl_xor(acc[i], 16);
            acc[i] += __shfl_xor(acc[i], 32);
        }
#pragma unroll
        for (int off = 32; off > 0; off >>= 1) {
            dn0 += __shfl_xor(dn0, off);
            dn1 += __shfl_xor(dn1, off);
            dn2 += __shfl_xor(dn2, off);
            dn3 += __shfl_xor(dn3, off);
        }
        const float dsel = (hsel == 0) ? dn0 : (hsel == 1) ? dn1 : (hsel == 2) ? dn2 : dn3;
        const float inv  = (dsel > 0.f) ? 1.0f / dsel : 0.f;
        if (grp == 0) {
            float* op = out + (size_t)gnode * OC + (lane16 << 3);
            *(float4*)(op)     = make_float4(acc[0]*inv, acc[1]*inv, acc[2]*inv, acc[3]*inv);
            *(float4*)(op + 4) = make_float4(acc[4]*inv, acc[5]*inv, acc[6]*inv, acc[7]*inv);
        }
    }
}

// ------------------------------------------------------------------- launcher
extern "C" void kernel_launch(void* const* d_in, const int* in_sizes, int n_in,
                              void* d_out, int out_size, void* d_ws, size_t ws_size,
                              hipStream_t stream) {
    const float* h_in = (const float*)d_in[0];
    const float* W    = (const float*)d_in[1];
    const float* a    = (const float*)d_in[2];
    const int*   src  = (const int*)d_in[3];
    const int*   dst  = (const int*)d_in[4];
    float*       out  = (float*)d_out;

    char* w = (char*)d_ws;
    __hip_bfloat16* zb = (__hip_bfloat16*)(w);          // 12,800,000 B
    float*    ssrc     = (float*)(w + 12800000);        //    800,000 B
    float*    sdst     = (float*)(w + 13600000);        //    800,000 B
    int*      cursor   = (int*)(w + 14400000);          //     50,048 B
    uint32_t* ebuf     = (uint32_t*)(w + 14450048);     //  8,007,680 B (782*2560*4)
    // total 22,457,728 B

    hipMemsetAsync(cursor, 0, NBUCK * CURS * 4, stream);

    k_front<<<GEMM_BLOCKS + BIN_BLOCKS, 256, 0, stream>>>(h_in, W, a, src, dst,
                                                          zb, ssrc, sdst, cursor, ebuf);
    k_gatb <<<NBUCK, 512, 0, stream>>>((const uint32_t*)zb,
                                       (const float4*)ssrc, (const float4*)sdst,
                                       cursor, ebuf, out);
}